// Round 6
// baseline (110.723 us; speedup 1.0000x reference)
//
#include <hip/hip_runtime.h>
#include <hip/hip_fp16.h>
#include <math.h>

#define HW 512
#define LOG2HW 9
#define NIMG 96       // N*C = 32*3
#define NBANDS 16
#define NCOL 257      // processed column pairs c = 0..256 (c-bar folded into weights)
#define PSTRIDE 518   // float2 stride per 512-FFT pack in LDS
#define CPSTR 520     // float2 stride per wave in colfft scratch (2 cols * 256 + pad)
#define IMG_E (256 * 512)   // half2 per image: [f:256][c:512]
#define PI_F 3.14159265358979323846f

// ---------- small complex helpers ----------
__device__ __forceinline__ float2 cadd(float2 a, float2 b){return make_float2(a.x+b.x, a.y+b.y);}
__device__ __forceinline__ float2 csub(float2 a, float2 b){return make_float2(a.x-b.x, a.y-b.y);}
__device__ __forceinline__ float2 cmul(float2 a, float2 b){return make_float2(a.x*b.x - a.y*b.y, a.x*b.y + a.y*b.x);}
__device__ __forceinline__ float2 mul_negi(float2 a){return make_float2(a.y, -a.x);}  // a * (-i)

// LDS swizzles (involutions, preserve low 2 bits for contiguity)
__device__ __forceinline__ int swz(int i)  { return i ^ (((i >> 6) & 7) << 2); }
__device__ __forceinline__ int p256(int i) { return i ^ ((((i >> 4) ^ (i >> 6)) & 3) << 2); }

// 8-point DFT, W8 = e^{-2*pi*i/8}
__device__ __forceinline__ void dft8(const float2 u[8], float2 v[8]) {
    const float R = 0.70710678118654752440f;
    float2 s0 = cadd(u[0], u[4]), s1 = cadd(u[2], u[6]);
    float2 d0 = csub(u[0], u[4]), d1 = csub(u[2], u[6]);
    float2 E0 = cadd(s0, s1), E2 = csub(s0, s1);
    float2 ni = mul_negi(d1);
    float2 E1 = cadd(d0, ni), E3 = csub(d0, ni);
    float2 t0 = cadd(u[1], u[5]), t1 = cadd(u[3], u[7]);
    float2 e0 = csub(u[1], u[5]), e1 = csub(u[3], u[7]);
    float2 O0 = cadd(t0, t1), O2 = csub(t0, t1);
    float2 mi = mul_negi(e1);
    float2 O1 = cadd(e0, mi), O3 = csub(e0, mi);
    float2 w1O = make_float2(R * (O1.x + O1.y), R * (O1.y - O1.x));
    float2 w2O = mul_negi(O2);
    float2 w3O = make_float2(R * (O3.y - O3.x), -R * (O3.x + O3.y));
    v[0] = cadd(E0, O0);  v[4] = csub(E0, O0);
    v[1] = cadd(E1, w1O); v[5] = csub(E1, w1O);
    v[2] = cadd(E2, w2O); v[6] = csub(E2, w2O);
    v[3] = cadd(E3, w3O); v[7] = csub(E3, w3O);
}

// 4-point DFT: v[s] = sum_e u[e] * (-i)^{s*e}
__device__ __forceinline__ void dft4(const float2 u[4], float2 v[4]) {
    float2 a = cadd(u[0], u[2]), b = csub(u[0], u[2]);
    float2 c = cadd(u[1], u[3]), d = mul_negi(csub(u[1], u[3]));
    v[0] = cadd(a, c); v[2] = csub(a, c);
    v[1] = cadd(b, d); v[3] = csub(b, d);
}

__device__ __forceinline__ void twiddle_mul8(float2 v[8], float ang) {
    float sn, cs;
    __sincosf(ang, &sn, &cs);
    float2 w1 = make_float2(cs, sn);
    float2 w2 = cmul(w1, w1), w3 = cmul(w2, w1), w4 = cmul(w2, w2);
    float2 w5 = cmul(w3, w2), w6 = cmul(w3, w3), w7 = cmul(w4, w3);
    v[1] = cmul(v[1], w1); v[2] = cmul(v[2], w2); v[3] = cmul(v[3], w3);
    v[4] = cmul(v[4], w4); v[5] = cmul(v[5], w5); v[6] = cmul(v[6], w6);
    v[7] = cmul(v[7], w7);
}

__device__ __forceinline__ void twiddle_mul4(float2 v[4], float ang) {
    float sn, cs;
    __sincosf(ang, &sn, &cs);
    float2 w1 = make_float2(cs, sn);
    float2 w2 = cmul(w1, w1), w3 = cmul(w2, w1);
    v[1] = cmul(v[1], w1); v[2] = cmul(v[2], w2); v[3] = cmul(v[3], w3);
}

// 512-pt DIF radix-8 FFT, one pack per WAVE (lane j), wave-private LDS.
// Input: u[e] = x[j + 64e]. Output: v[s] = X[dr9(8j+s)].
__device__ __forceinline__ void fft512_wave(float2* zz, float2 u[8], float2 v[8], int j) {
    dft8(u, v);
    twiddle_mul8(v, -(2.0f * PI_F / 512.0f) * (float)j);
    #pragma unroll
    for (int s = 0; s < 8; ++s) zz[swz(j + 64 * s)] = v[s];
    __builtin_amdgcn_wave_barrier();
    const int sb = j >> 3, r = j & 7;
    #pragma unroll
    for (int e = 0; e < 8; ++e) u[e] = zz[swz(64 * sb + r + 8 * e)];
    __builtin_amdgcn_wave_barrier();
    dft8(u, v);
    twiddle_mul8(v, -(2.0f * PI_F / 64.0f) * (float)r);
    #pragma unroll
    for (int s = 0; s < 8; ++s) zz[swz(64 * sb + r + 8 * s)] = v[s];
    __builtin_amdgcn_wave_barrier();
    #pragma unroll
    for (int e = 0; e < 8; ++e) u[e] = zz[swz(8 * j + e)];
    __builtin_amdgcn_wave_barrier();
    dft8(u, v);
}

// ---------- weight precompute ----------
// wmapk[k1*512+k2] = sum_b bw[b]*mask[b][(k1+256)%512][(k2+256)%512]
__global__ void wmapk_kernel(const float* __restrict__ bw,
                             const float* __restrict__ masks,
                             float* __restrict__ wmapk) {
    int idx = blockIdx.x * 256 + threadIdx.x;
    int k1 = idx >> LOG2HW, k2 = idx & (HW - 1);
    int p1 = (k1 + HW / 2) & (HW - 1);
    int p2 = (k2 + HW / 2) & (HW - 1);
    int off = p1 * HW + p2;
    float s = 0.f;
    #pragma unroll
    for (int b = 0; b < NBANDS; ++b)
        s += bw[b] * masks[b * HW * HW + off];
    wmapk[idx] = s;
}

// wq[c*512 + k1]: Hermitian-folded weight (columns c and 512-c merged),
// natural (k1, c) indexing; includes ortho norm 1/512^2.
__global__ void wfold_kernel(const float* __restrict__ wmapk,
                             float* __restrict__ wq) {
    int idx = blockIdx.x * 256 + threadIdx.x;     // c*512 + k1
    if (idx >= NCOL * HW) return;
    int c = idx >> LOG2HW, k1 = idx & (HW - 1);
    float s = wmapk[k1 * HW + c];
    if (c >= 1 && c <= 255)
        s += wmapk[((HW - k1) & (HW - 1)) * HW + (HW - c)];
    wq[idx] = s * (1.0f / (512.0f * 512.0f));
}

// ---------- row pass (fully wave-private, NO __syncthreads) ----------
// Wave = one pack f: rows 2f (real) + 2f+1 (imag). 512-pt packed FFT,
// natural-order bounce in wave LDS, contiguous 32 B f16 store of Z_f(0..511).
__global__ __launch_bounds__(256)
void rowfft_kernel(const float* __restrict__ pred,
                   const float* __restrict__ gt,
                   __half2* __restrict__ fdata, int img0) {
    __shared__ float2 z[4 * PSTRIDE];
    const int limg = blockIdx.y;
    const int t = threadIdx.x;
    const int wv = t >> 6, j = t & 63;
    const int img = img0 + limg;
    const int f = blockIdx.x * 4 + wv;          // pack 0..255

    float2* zz = z + wv * PSTRIDE;
    const size_t rbase = ((size_t)img * HW + 2 * f) * HW;
    const float4* pA = (const float4*)(pred + rbase);
    const float4* gA = (const float4*)(gt + rbase);
    const float4* pB = (const float4*)(pred + rbase + HW);
    const float4* gB = (const float4*)(gt + rbase + HW);

    // coalesced float4 loads -> packed err (re=row 2f, im=row 2f+1) in LDS
    #pragma unroll
    for (int it = 0; it < 2; ++it) {
        int c4 = j + 64 * it;                 // float4 chunk 0..127
        float4 a = pA[c4], b = gA[c4], d = pB[c4], e4 = gB[c4];
        float4* dst = (float4*)(zz + swz(4 * c4));
        dst[0] = make_float4(a.x - b.x, d.x - e4.x, a.y - b.y, d.y - e4.y);
        dst[1] = make_float4(a.z - b.z, d.z - e4.z, a.w - b.w, d.w - e4.w);
    }
    __builtin_amdgcn_wave_barrier();

    float2 u[8], v[8];
    #pragma unroll
    for (int e = 0; e < 8; ++e) u[e] = zz[swz(j + 64 * e)];
    __builtin_amdgcn_wave_barrier();
    fft512_wave(zz, u, v, j);
    __builtin_amdgcn_wave_barrier();

    // natural-order bounce: v[s] = Z[dr9(8j+s)] = Z[64s + m]
    const int m = 8 * (j & 7) + (j >> 3);
    #pragma unroll
    for (int s = 0; s < 8; ++s) zz[swz(64 * s + m)] = v[s];
    __builtin_amdgcn_wave_barrier();

    // lane j stores Z(8j..8j+7) as 8 half2 = two 16 B stores, contiguous
    union Pack { __half2 h[8]; uint4 q[2]; } pk;
    #pragma unroll
    for (int i = 0; i < 8; ++i) {
        float2 cv = zz[swz(8 * j + i)];
        pk.h[i] = __floats2half2_rn(cv.x, cv.y);
    }
    uint4* outp = (uint4*)(fdata + (size_t)limg * IMG_E + (size_t)f * HW + 8 * j);
    outp[0] = pk.q[0];
    outp[1] = pk.q[1];
}

// ---------- column pass ----------
// Block = 512 threads = 8 waves; wave w owns column pair (c, 512-c),
// c = c0 + w. Tile-stage both column groups through LDS (one barrier),
// then per wave: two 256-pt FFTs over packs f (4 regs each, radix-4 x4),
// natural-order bounce, Hermitian E/O unpack + radix-2 combine to the
// true spectrum F(k1,c), weighted power sum, shfl-reduce.
__global__ __launch_bounds__(512)
void colfft_kernel(const __half2* __restrict__ fdata,
                   const float* __restrict__ wq,
                   float* __restrict__ partials, int img0) {
    __shared__ __half2 tile[2][256 * 9];      // [L/R][f*9 + i], padded pitch
    __shared__ float2 scr[8 * CPSTR];
    const int limg = blockIdx.y;
    const int t = threadIdx.x;
    const int wv = t >> 6, j = t & 63;
    const int c0 = blockIdx.x * 8;
    const __half2* base = fdata + (size_t)limg * IMG_E;

    // cooperative tile load: thread t covers (f = t>>3 + 64*it, i = t&7)
    #pragma unroll
    for (int it = 0; it < 4; ++it) {
        int f = (t >> 3) + 64 * it, i = t & 7;
        int cL = c0 + i;                       // <= 263, valid
        int cR = (HW - c0 - i) & (HW - 1);
        tile[0][f * 9 + i] = base[f * HW + cL];
        tile[1][f * 9 + i] = base[f * HW + cR];
    }
    __syncthreads();

    const int c = c0 + wv;
    if (c > 256) return;                       // surplus waves exit (post-barrier)

    float2* s = scr + wv * CPSTR;              // [0..255]=L, [256..511]=R
    float2 uL[4], uR[4], vL[4], vR[4];
    #pragma unroll
    for (int e = 0; e < 4; ++e) {
        __half2 hL = tile[0][(j + 64 * e) * 9 + wv];
        __half2 hR = tile[1][(j + 64 * e) * 9 + wv];
        uL[e] = make_float2(__low2float(hL), __high2float(hL));
        uR[e] = make_float2(__low2float(hR), __high2float(hR));
    }

    // ---- stage 1 (N=256) ----
    dft4(uL, vL); dft4(uR, vR);
    { float ang = -(2.0f * PI_F / 256.0f) * (float)j;
      twiddle_mul4(vL, ang); twiddle_mul4(vR, ang); }
    #pragma unroll
    for (int k = 0; k < 4; ++k) {
        s[p256(64 * k + j)] = vL[k];
        s[256 + p256(64 * k + j)] = vR[k];
    }
    __builtin_amdgcn_wave_barrier();
    // ---- stage 2 (N=64) ----
    const int h = j >> 4, m2 = j & 15;
    #pragma unroll
    for (int e = 0; e < 4; ++e) {
        uL[e] = s[p256(64 * h + m2 + 16 * e)];
        uR[e] = s[256 + p256(64 * h + m2 + 16 * e)];
    }
    __builtin_amdgcn_wave_barrier();
    dft4(uL, vL); dft4(uR, vR);
    { float ang = -(2.0f * PI_F / 64.0f) * (float)m2;
      twiddle_mul4(vL, ang); twiddle_mul4(vR, ang); }
    #pragma unroll
    for (int k = 0; k < 4; ++k) {
        s[p256(64 * h + 16 * k + m2)] = vL[k];
        s[256 + p256(64 * h + 16 * k + m2)] = vR[k];
    }
    __builtin_amdgcn_wave_barrier();
    // ---- stage 3 (N=16) ----
    const int s2 = (j >> 2) & 3, m3 = j & 3;
    #pragma unroll
    for (int e = 0; e < 4; ++e) {
        uL[e] = s[p256(64 * h + 16 * s2 + m3 + 4 * e)];
        uR[e] = s[256 + p256(64 * h + 16 * s2 + m3 + 4 * e)];
    }
    __builtin_amdgcn_wave_barrier();
    dft4(uL, vL); dft4(uR, vR);
    { float ang = -(2.0f * PI_F / 16.0f) * (float)m3;
      twiddle_mul4(vL, ang); twiddle_mul4(vR, ang); }
    #pragma unroll
    for (int k = 0; k < 4; ++k) {
        s[p256(64 * h + 16 * s2 + 4 * k + m3)] = vL[k];
        s[256 + p256(64 * h + 16 * s2 + 4 * k + m3)] = vR[k];
    }
    __builtin_amdgcn_wave_barrier();
    // ---- stage 4 (N=4) + natural-order store ----
    #pragma unroll
    for (int e = 0; e < 4; ++e) {
        uL[e] = s[p256(4 * j + e)];
        uR[e] = s[256 + p256(4 * j + e)];
    }
    __builtin_amdgcn_wave_barrier();
    dft4(uL, vL); dft4(uR, vR);
    const int nb = 16 * (j & 3) + 4 * ((j >> 2) & 3) + (j >> 4);
    #pragma unroll
    for (int k = 0; k < 4; ++k) {
        s[p256(64 * k + nb)] = vL[k];          // G_c at natural q
        s[256 + p256(64 * k + nb)] = vR[k];    // G_cbar at natural q
    }
    __builtin_amdgcn_wave_barrier();

    // Hermitian unpack + combine + weighted power:
    // E(q) = (G_c(q) + conj(G_cb(-q)))/2 ; O(q) = (G_c(q) - conj(G_cb(-q)))/(2i)
    // F(q,c) = E + W^q O ; F(q+256,c) = E - W^q O ; W = e^{-2pi i/512}
    const float* wc = wq + (size_t)c * HW;
    float acc = 0.f;
    #pragma unroll
    for (int e = 0; e < 4; ++e) {
        int q = j + 64 * e;
        float2 GL = s[p256(q)];
        float2 GR = s[256 + p256((256 - q) & 255)];
        float2 E = make_float2(0.5f * (GL.x + GR.x), 0.5f * (GL.y - GR.y));
        float2 D = make_float2(GL.x - GR.x, GL.y + GR.y);   // GL - conj(GR)
        float2 O = make_float2(0.5f * D.y, -0.5f * D.x);    // D * (-i/2)
        float sn, cs;
        __sincosf(-(PI_F / 256.0f) * (float)q, &sn, &cs);
        float2 WO = make_float2(cs * O.x - sn * O.y, cs * O.y + sn * O.x);
        float2 F1 = cadd(E, WO), F2 = csub(E, WO);
        acc += (F1.x * F1.x + F1.y * F1.y) * wc[q];
        acc += (F2.x * F2.x + F2.y * F2.y) * wc[q + 256];
    }
    #pragma unroll
    for (int off = 32; off > 0; off >>= 1)
        acc += __shfl_down(acc, off, 64);
    if (j == 0)
        partials[(size_t)(img0 + limg) * NCOL + c] = acc;
}

__global__ void final_reduce(const float* __restrict__ partials,
                             float* __restrict__ out) {
    __shared__ float red[256];
    const int t = threadIdx.x;
    float acc = 0.f;
    for (int i = t; i < NIMG * NCOL; i += 256) acc += partials[i];
    red[t] = acc;
    __syncthreads();
    #pragma unroll
    for (int s = 128; s > 0; s >>= 1) {
        if (t < s) red[t] += red[t + s];
        __syncthreads();
    }
    if (t == 0) out[0] = red[0] * (1.0f / 25165824.0f);  // / (N*C*H*W)
}

extern "C" void kernel_launch(void* const* d_in, const int* in_sizes, int n_in,
                              void* d_out, int out_size, void* d_ws, size_t ws_size,
                              hipStream_t stream) {
    const float* pred  = (const float*)d_in[0];
    const float* gt    = (const float*)d_in[1];
    const float* bw    = (const float*)d_in[2];
    const float* masks = (const float*)d_in[3];
    float* out = (float*)d_out;

    char* ws = (char*)d_ws;
    float* wmapk    = (float*)ws;                             // 1 MiB
    float* wq       = (float*)(ws + (1 << 20));               // 526,336 B
    float* partials = (float*)(ws + (1 << 20) + (576 << 10)); // 98,688 B
    __half2* fdata  = (__half2*)(ws + (2 << 20));
    const size_t fixed = (2 << 20);
    const size_t img_bytes = (size_t)IMG_E * sizeof(__half2); // 512 KiB

    int chunk = 1;
    if (ws_size > fixed + img_bytes)
        chunk = (int)((ws_size - fixed) / img_bytes);
    if (chunk > NIMG) chunk = NIMG;
    if (chunk < 1) chunk = 1;

    wmapk_kernel<<<(HW * HW) / 256, 256, 0, stream>>>(bw, masks, wmapk);
    wfold_kernel<<<(NCOL * HW + 255) / 256, 256, 0, stream>>>(wmapk, wq);

    for (int img0 = 0; img0 < NIMG; img0 += chunk) {
        int n = NIMG - img0 < chunk ? NIMG - img0 : chunk;
        rowfft_kernel<<<dim3(64, n), 256, 0, stream>>>(pred, gt, fdata, img0);
        colfft_kernel<<<dim3((NCOL + 7) / 8, n), 512, 0, stream>>>(fdata, wq, partials, img0);
    }

    final_reduce<<<1, 256, 0, stream>>>(partials, out);
}